// Round 1
// baseline (173.469 us; speedup 1.0000x reference)
//
#include <hip/hip_runtime.h>
#include <hip/hip_bf16.h>

#define N_ROWS 8192
#define D_DIM  256

// loss_i = log(sum_{j != i} exp(<x_i,y_j>/T)) - <x_i,y_i>/T ; out = mean_i loss_i
static constexpr float kScaleLog2 = 20.609929155556627f;  // (1/0.07) * log2(e)
static constexpr float kInvT      = 14.285714285714286f;  // 1/0.07

typedef __bf16 bf16x8 __attribute__((ext_vector_type(8)));
typedef float  f32x4  __attribute__((ext_vector_type(4)));

// ---------------- fp32 -> bf16 pre-convert (one pass, both inputs) -------------
__global__ __launch_bounds__(256)
void cvt_bf16_kernel(const float* __restrict__ x, const float* __restrict__ y,
                     __bf16* __restrict__ xb, __bf16* __restrict__ yb) {
  const int per_mat = N_ROWS * D_DIM / 8;  // 8 elements per thread
  int idx = blockIdx.x * blockDim.x + threadIdx.x;
  const float* src = x;
  __bf16* dst = xb;
  int i = idx;
  if (idx >= per_mat) { src = y; dst = yb; i = idx - per_mat; }
  float4 a = ((const float4*)src)[2 * (size_t)i];
  float4 b = ((const float4*)src)[2 * (size_t)i + 1];
  bf16x8 v;
  v[0] = (__bf16)a.x; v[1] = (__bf16)a.y; v[2] = (__bf16)a.z; v[3] = (__bf16)a.w;
  v[4] = (__bf16)b.x; v[5] = (__bf16)b.y; v[6] = (__bf16)b.z; v[7] = (__bf16)b.w;
  *(bf16x8*)(dst + (size_t)i * 8) = v;
}

// ---------------- fused GEMM + exp + row-sum ----------------------------------
// Block tile 128x128, BK=64, 256 threads = 4 waves (2x2), wave tile 64x64
// via 4x4 MFMA 16x16x32 bf16. LDS: XOR-swizzled 16B chunks, stride 64 elems.
__global__ __launch_bounds__(256, 2)
void infonce_gemm(const __bf16* __restrict__ X, const __bf16* __restrict__ Y,
                  float* __restrict__ rowsum, float* __restrict__ diag) {
  constexpr int BM = 128, BK = 64;
  __shared__ __bf16 Xs[BM * BK];
  __shared__ __bf16 Ys[BM * BK];

  const int bi = blockIdx.y;   // row tile of X
  const int bj = blockIdx.x;   // row tile of Y (= column tile of S)
  const int t    = threadIdx.x;
  const int lane = t & 63;
  const int wave = t >> 6;            // 0..3
  const int wm   = wave >> 1;         // 0..1
  const int wn   = wave & 1;          // 0..1
  const int quad = lane >> 4;         // 0..3
  const int l15  = lane & 15;

  const __bf16* Xblk = X + (size_t)(bi * BM) * D_DIM;
  const __bf16* Yblk = Y + (size_t)(bj * BM) * D_DIM;

  f32x4 acc[4][4];
#pragma unroll
  for (int a = 0; a < 4; ++a)
#pragma unroll
    for (int b = 0; b < 4; ++b) acc[a][b] = (f32x4){0.f, 0.f, 0.f, 0.f};

  for (int kt = 0; kt < D_DIM / BK; ++kt) {
    if (kt) __syncthreads();
    const int k0 = kt * BK;
    // stage: 1024 16B-chunks per matrix, 4 per thread per matrix
#pragma unroll
    for (int it = 0; it < 4; ++it) {
      int idx = t + it * 256;
      int row = idx >> 3;        // 0..127
      int ch  = idx & 7;         // 0..7 (8 bf16 each)
      int chs = ch ^ (row & 7);  // swizzle
      bf16x8 vx = *(const bf16x8*)(Xblk + (size_t)row * D_DIM + k0 + ch * 8);
      *(bf16x8*)(&Xs[row * BK + chs * 8]) = vx;
      bf16x8 vy = *(const bf16x8*)(Yblk + (size_t)row * D_DIM + k0 + ch * 8);
      *(bf16x8*)(&Ys[row * BK + chs * 8]) = vy;
    }
    __syncthreads();

#pragma unroll
    for (int ks = 0; ks < 2; ++ks) {  // two k=32 steps per BK
      bf16x8 af[4], bfr[4];
#pragma unroll
      for (int mt = 0; mt < 4; ++mt) {
        int row = wm * 64 + mt * 16 + l15;
        int ch  = ks * 4 + quad;
        int chs = ch ^ (row & 7);
        af[mt] = *(const bf16x8*)(&Xs[row * BK + chs * 8]);
      }
#pragma unroll
      for (int nt = 0; nt < 4; ++nt) {
        int row = wn * 64 + nt * 16 + l15;
        int ch  = ks * 4 + quad;
        int chs = ch ^ (row & 7);
        bfr[nt] = *(const bf16x8*)(&Ys[row * BK + chs * 8]);
      }
#pragma unroll
      for (int mt = 0; mt < 4; ++mt)
#pragma unroll
        for (int nt = 0; nt < 4; ++nt)
          acc[mt][nt] = __builtin_amdgcn_mfma_f32_16x16x32_bf16(
              af[mt], bfr[nt], acc[mt][nt], 0, 0, 0);
    }
  }

  // epilogue: exp + row-sum (excluding diagonal), diag capture
  const int gi_base = bi * BM + wm * 64;
  const int gj_base = bj * BM + wn * 64;
#pragma unroll
  for (int mt = 0; mt < 4; ++mt) {
#pragma unroll
    for (int r = 0; r < 4; ++r) {
      const int gi = gi_base + mt * 16 + quad * 4 + r;
      float part = 0.f;
#pragma unroll
      for (int nt = 0; nt < 4; ++nt) {
        const int gj = gj_base + nt * 16 + l15;
        float s = acc[mt][nt][r];
        if (gi == gj) {
          diag[gi] = s;           // unique writer
        } else {
          part += exp2f(s * kScaleLog2);
        }
      }
      // reduce across the 16 lanes holding this row
      part += __shfl_xor(part, 1);
      part += __shfl_xor(part, 2);
      part += __shfl_xor(part, 4);
      part += __shfl_xor(part, 8);
      if (l15 == 0) atomicAdd(&rowsum[gi], part);
    }
  }
}

// ---------------- finalize: loss = mean(log(rowsum_i) - diag_i/T) --------------
__global__ __launch_bounds__(256)
void finalize_kernel(const float* __restrict__ rowsum,
                     const float* __restrict__ diag, float* __restrict__ out) {
  __shared__ float red[256];
  int t = threadIdx.x;
  float local = 0.f;
  for (int i = t; i < N_ROWS; i += 256)
    local += __logf(rowsum[i]) - diag[i] * kInvT;
  red[t] = local;
  __syncthreads();
  for (int s = 128; s > 0; s >>= 1) {
    if (t < s) red[t] += red[t + s];
    __syncthreads();
  }
  if (t == 0) out[0] = red[0] / (float)N_ROWS;
}

extern "C" void kernel_launch(void* const* d_in, const int* in_sizes, int n_in,
                              void* d_out, int out_size, void* d_ws, size_t ws_size,
                              hipStream_t stream) {
  const float* x = (const float*)d_in[0];
  const float* y = (const float*)d_in[1];
  float* out = (float*)d_out;

  // ws layout: rowsum[N] f32 | diag[N] f32 | xb[N*D] bf16 | yb[N*D] bf16  (~8.4 MB)
  float* rowsum = (float*)d_ws;
  float* diag   = rowsum + N_ROWS;
  __bf16* xb = (__bf16*)((char*)d_ws + 2 * N_ROWS * sizeof(float));
  __bf16* yb = xb + (size_t)N_ROWS * D_DIM;

  hipMemsetAsync(rowsum, 0, N_ROWS * sizeof(float), stream);

  int cvt_blocks = 2 * N_ROWS * D_DIM / 8 / 256;  // 2048
  cvt_bf16_kernel<<<cvt_blocks, 256, 0, stream>>>(x, y, xb, yb);

  dim3 grid(N_ROWS / 128, N_ROWS / 128);  // 64 x 64
  infonce_gemm<<<grid, 256, 0, stream>>>(xb, yb, rowsum, diag);

  finalize_kernel<<<1, 256, 0, stream>>>(rowsum, diag, out);
}